// Round 1
// baseline (1280.146 us; speedup 1.0000x reference)
//
#include <hip/hip_runtime.h>

// Masked attention, B=8, NQ=1024, S=2048, D=512, fp32 in/out.
// Flash-style online masked softmax. QK^T via split-bf16 (hi+lo, 3 MFMAs)
// for near-fp32 score precision; PV via single bf16 MFMA.
// Grid: 256 WGs = 8 batches x 32 q-tiles (QT=32). 4 waves/WG.
// Wave w: row-tile rw=w&1 (16 q rows), QK col-tile cw=w>>1 (16 s cols),
//         PV d-half cw (256 of 512 dims).

#define Bz 8
#define NQz 1024
#define Sz 2048
#define Dz 512
#define QT 32
#define TS 32
#define KP 520   // K row stride in LDS (elements), pad 8 -> 1040B rows, 16B aligned
#define VP 40    // Vt row stride, pad 8 -> 80B rows, 16B aligned
#define PP 40    // P row stride

typedef short bf16x8 __attribute__((ext_vector_type(8)));
typedef float f32x4 __attribute__((ext_vector_type(4)));

__device__ __forceinline__ unsigned short f2bf(float x) {
  unsigned u = __builtin_bit_cast(unsigned, x);
  unsigned r = (u + 0x7FFFu + ((u >> 16) & 1u)) >> 16;  // RNE
  return (unsigned short)r;
}
__device__ __forceinline__ float bf2f(unsigned short h) {
  unsigned u = ((unsigned)h) << 16;
  return __builtin_bit_cast(float, u);
}

__global__ __launch_bounds__(256, 1)
void attn_flash(const float* __restrict__ Q, const float* __restrict__ K,
                const float* __restrict__ V, const int* __restrict__ Msk,
                float* __restrict__ Out) {
  __shared__ alignas(16) unsigned short sKhi[TS][KP];
  __shared__ alignas(16) unsigned short sKlo[TS][KP];
  __shared__ alignas(16) unsigned short sVt[Dz][VP];
  __shared__ alignas(16) unsigned short sP[QT][PP];
  __shared__ float sTMax[2][QT];
  __shared__ float sTSum[2][QT];
  __shared__ float sM[QT];
  __shared__ float sL[QT];

  const int tid  = threadIdx.x;
  const int wave = tid >> 6;
  const int lane = tid & 63;
  const int l16  = lane & 15;
  const int quad = lane >> 4;
  const int rw   = wave & 1;   // q row-tile
  const int cw   = wave >> 1;  // s col-tile (QK) / d half (PV)
  const int b    = blockIdx.x >> 5;
  const int qt   = blockIdx.x & 31;
  const int q0   = qt * QT;

  const float* Qb = Q + ((size_t)b * NQz + q0) * Dz;
  const float* Kb = K + (size_t)b * Sz * Dz;
  const float* Vb = V + (size_t)b * Sz * Dz;
  const int*   Mb = Msk + ((size_t)b * NQz + q0) * (size_t)Sz;

  // ---- Q A-fragments in registers, hi/lo bf16 split (rows rw*16+l16) ----
  bf16x8 qhi[16], qlo[16];
  {
    const float* qrow = Qb + (size_t)(rw * 16 + l16) * Dz;
    #pragma unroll
    for (int kk = 0; kk < 16; ++kk) {
      const float4 a = *(const float4*)(qrow + kk * 32 + quad * 8);
      const float4 c = *(const float4*)(qrow + kk * 32 + quad * 8 + 4);
      float v[8] = {a.x, a.y, a.z, a.w, c.x, c.y, c.z, c.w};
      bf16x8 h, l;
      #pragma unroll
      for (int j = 0; j < 8; ++j) {
        unsigned short hb = f2bf(v[j]);
        h[j] = (short)hb;
        l[j] = (short)f2bf(v[j] - bf2f(hb));
      }
      qhi[kk] = h;
      qlo[kk] = l;
    }
  }

  if (tid < QT) { sM[tid] = -1e30f; sL[tid] = 0.0f; }

  f32x4 oacc[16];
  #pragma unroll
  for (int t = 0; t < 16; ++t) oacc[t] = (f32x4){0.f, 0.f, 0.f, 0.f};

  for (int s0 = 0; s0 < Sz; s0 += TS) {
    __syncthreads();  // prior-iter LDS reads done; sM/sL updates visible

    // ---- stage K tile (hi/lo bf16), rows = s, contiguous d ----
    #pragma unroll
    for (int i = 0; i < 16; ++i) {
      int idx = tid + 256 * i;     // 0..4095
      int row = idx >> 7;          // 0..31 (s within tile)
      int d4  = (idx & 127) * 4;   // 0..508
      const float4 kv = *(const float4*)(Kb + (size_t)(s0 + row) * Dz + d4);
      float vv[4] = {kv.x, kv.y, kv.z, kv.w};
      unsigned short hi[4], lo[4];
      #pragma unroll
      for (int j = 0; j < 4; ++j) {
        hi[j] = f2bf(vv[j]);
        lo[j] = f2bf(vv[j] - bf2f(hi[j]));
      }
      uint2 hw, lw;
      hw.x = (unsigned)hi[0] | ((unsigned)hi[1] << 16);
      hw.y = (unsigned)hi[2] | ((unsigned)hi[3] << 16);
      lw.x = (unsigned)lo[0] | ((unsigned)lo[1] << 16);
      lw.y = (unsigned)lo[2] | ((unsigned)lo[3] << 16);
      *(uint2*)(&sKhi[row][d4]) = hw;
      *(uint2*)(&sKlo[row][d4]) = lw;
    }
    // ---- stage V tile transposed: sVt[d][s] ----
    #pragma unroll
    for (int i = 0; i < 16; ++i) {
      int idx = tid + 256 * i;
      int row = idx >> 7;          // s
      int d4  = (idx & 127) * 4;   // d
      const float4 vv = *(const float4*)(Vb + (size_t)(s0 + row) * Dz + d4);
      sVt[d4 + 0][row] = f2bf(vv.x);
      sVt[d4 + 1][row] = f2bf(vv.y);
      sVt[d4 + 2][row] = f2bf(vv.z);
      sVt[d4 + 3][row] = f2bf(vv.w);
    }
    __syncthreads();

    // ---- QK^T: tile (rw, cw), 3-MFMA split over 16 k-steps ----
    f32x4 sc = (f32x4){0.f, 0.f, 0.f, 0.f};
    {
      const unsigned short* kh = &sKhi[cw * 16 + l16][quad * 8];
      const unsigned short* kl = &sKlo[cw * 16 + l16][quad * 8];
      #pragma unroll
      for (int kk = 0; kk < 16; ++kk) {
        bf16x8 bh = *(const bf16x8*)(kh + kk * 32);
        bf16x8 bl = *(const bf16x8*)(kl + kk * 32);
        sc = __builtin_amdgcn_mfma_f32_16x16x32_bf16(qhi[kk], bh, sc, 0, 0, 0);
        sc = __builtin_amdgcn_mfma_f32_16x16x32_bf16(qhi[kk], bl, sc, 0, 0, 0);
        sc = __builtin_amdgcn_mfma_f32_16x16x32_bf16(qlo[kk], bh, sc, 0, 0, 0);
      }
    }

    // ---- mask + per-row tile max (C-frag row = quad*4+r, col = l16) ----
    int   msk[4];
    float se[4];
    #pragma unroll
    for (int r = 0; r < 4; ++r) {
      int qrow = rw * 16 + quad * 4 + r;
      msk[r] = Mb[(size_t)qrow * Sz + s0 + cw * 16 + l16];
      se[r]  = msk[r] ? sc[r] : -1e30f;
    }
    float rmax[4] = {se[0], se[1], se[2], se[3]};
    #pragma unroll
    for (int d = 1; d < 16; d <<= 1) {
      #pragma unroll
      for (int r = 0; r < 4; ++r) rmax[r] = fmaxf(rmax[r], __shfl_xor(rmax[r], d));
    }
    if (l16 == 0) {
      #pragma unroll
      for (int r = 0; r < 4; ++r) sTMax[cw][rw * 16 + quad * 4 + r] = rmax[r];
    }
    __syncthreads();

    // ---- m_new, alpha, P, partial row sums ----
    float mnew[4], alpha[4], rsum[4];
    #pragma unroll
    for (int r = 0; r < 4; ++r) {
      int row = rw * 16 + quad * 4 + r;
      float mo = sM[row];
      float mn = fmaxf(mo, fmaxf(sTMax[0][row], sTMax[1][row]));
      mnew[r]  = mn;
      alpha[r] = __expf(mo - mn);
      float pv = msk[r] ? __expf(sc[r] - mn) : 0.0f;
      unsigned short pb = f2bf(pv);
      sP[row][cw * 16 + l16] = pb;
      rsum[r] = bf2f(pb);  // sum the rounded value for exact renorm consistency
    }
    #pragma unroll
    for (int d = 1; d < 16; d <<= 1) {
      #pragma unroll
      for (int r = 0; r < 4; ++r) rsum[r] += __shfl_xor(rsum[r], d);
    }
    if (l16 == 0) {
      #pragma unroll
      for (int r = 0; r < 4; ++r) sTSum[cw][rw * 16 + quad * 4 + r] = rsum[r];
    }
    __syncthreads();

    // ---- state owners (cw==0) update running m, l ----
    if (cw == 0 && l16 == 0) {
      #pragma unroll
      for (int r = 0; r < 4; ++r) {
        int row = rw * 16 + quad * 4 + r;
        sL[row] = alpha[r] * sL[row] + sTSum[0][row] + sTSum[1][row];
        sM[row] = mnew[r];
      }
    }

    // ---- rescale O, then O += P·V ----
    #pragma unroll
    for (int t = 0; t < 16; ++t) {
      #pragma unroll
      for (int r = 0; r < 4; ++r) oacc[t][r] *= alpha[r];
    }
    bf16x8 pa = *(const bf16x8*)(&sP[rw * 16 + l16][quad * 8]);
    #pragma unroll
    for (int t = 0; t < 16; ++t) {
      bf16x8 vb = *(const bf16x8*)(&sVt[cw * 256 + t * 16 + l16][quad * 8]);
      oacc[t] = __builtin_amdgcn_mfma_f32_16x16x32_bf16(pa, vb, oacc[t], 0, 0, 0);
    }
  }

  __syncthreads();  // final sL visible
  float linv[4];
  #pragma unroll
  for (int r = 0; r < 4; ++r) linv[r] = 1.0f / sL[rw * 16 + quad * 4 + r];
  #pragma unroll
  for (int t = 0; t < 16; ++t) {
    #pragma unroll
    for (int r = 0; r < 4; ++r) {
      Out[((size_t)b * NQz + q0 + rw * 16 + quad * 4 + r) * Dz + cw * 256 + t * 16 + l16] =
          oacc[t][r] * linv[r];
    }
  }
}

extern "C" void kernel_launch(void* const* d_in, const int* in_sizes, int n_in,
                              void* d_out, int out_size, void* d_ws, size_t ws_size,
                              hipStream_t stream) {
  const float* Q = (const float*)d_in[0];
  const float* K = (const float*)d_in[1];
  const float* V = (const float*)d_in[2];
  const int*   M = (const int*)d_in[3];
  float* O = (float*)d_out;
  attn_flash<<<dim3(Bz * (NQz / QT)), dim3(256), 0, stream>>>(Q, K, V, M, O);
}

// Round 2
// 427.127 us; speedup vs baseline: 2.9971x; 2.9971x over previous
//
#include <hip/hip_runtime.h>

// Masked attention B=8, NQ=1024, S=2048, D=512, fp32 in/out.
// Pipeline: prep_k (K->Khi/Klo bf16), prep_v (V->Vt bf16 transposed),
// attn_flash (flash online masked softmax, split-bf16 QK = 3 MFMAs, bf16 PV),
// combine (merge the 2 S-halves).
// attn: QT=64 q rows/WG, 8 waves, TS=32 s-tile, S-split=2 -> 256 WGs.

#define Bz 8
#define NQz 1024
#define Sz 2048
#define Dz 512
#define QT 64
#define TS 32
#define KP 520   // sK row pitch (ushort): 1040B = 65*16B -> b128-aligned rows, 2-way banks (free)
#define VP 40    // sVt row pitch: 80B -> 2-way banks (free)
#define PP 40

typedef short bf16x8 __attribute__((ext_vector_type(8)));
typedef float f32x4 __attribute__((ext_vector_type(4)));
typedef unsigned short ushort_t;

__device__ __forceinline__ unsigned short f2bf(float x) {
  unsigned u = __builtin_bit_cast(unsigned, x);
  unsigned r = (u + 0x7FFFu + ((u >> 16) & 1u)) >> 16;  // RNE
  return (unsigned short)r;
}
__device__ __forceinline__ float bf2f(unsigned short h) {
  unsigned u = ((unsigned)h) << 16;
  return __builtin_bit_cast(float, u);
}

// ---------------- prep 1: K fp32 -> Khi, Klo bf16 (row-major) ----------------
__global__ __launch_bounds__(256)
void prep_k(const float* __restrict__ K, ushort_t* __restrict__ Khi,
            ushort_t* __restrict__ Klo) {
  size_t e = ((size_t)blockIdx.x * 256 + threadIdx.x) * 4;
  float4 v = *(const float4*)(K + e);
  float vv[4] = {v.x, v.y, v.z, v.w};
  unsigned short h[4], l[4];
#pragma unroll
  for (int j = 0; j < 4; ++j) {
    h[j] = f2bf(vv[j]);
    l[j] = f2bf(vv[j] - bf2f(h[j]));
  }
  uint2 hw, lw;
  hw.x = (unsigned)h[0] | ((unsigned)h[1] << 16);
  hw.y = (unsigned)h[2] | ((unsigned)h[3] << 16);
  lw.x = (unsigned)l[0] | ((unsigned)l[1] << 16);
  lw.y = (unsigned)l[2] | ((unsigned)l[3] << 16);
  *(uint2*)(Khi + e) = hw;
  *(uint2*)(Klo + e) = lw;
}

// ---------------- prep 2: V fp32 [b][s][d] -> Vt bf16 [b][d][s] ----------------
__global__ __launch_bounds__(256)
void prep_v(const float* __restrict__ V, ushort_t* __restrict__ Vt) {
  __shared__ ushort_t sT[32][72];  // 32 s x 64 d tile, padded
  const int t = threadIdx.x;
  const int bx = blockIdx.x;
  const int b = bx >> 9;
  const int rest = bx & 511;
  const int st = rest >> 3;  // 0..63
  const int dt = rest & 7;   // 0..7
  const int s0 = st * 32, d0 = dt * 64;
  const float* Vb = V + ((size_t)b * Sz + s0) * Dz + d0;
#pragma unroll
  for (int i = 0; i < 2; ++i) {
    int idx = t + 256 * i;          // 0..511
    int s = idx >> 4;               // 0..31
    int dc = (idx & 15) * 4;        // 0..60
    float4 v = *(const float4*)(Vb + (size_t)s * Dz + dc);
    uint2 w;
    w.x = (unsigned)f2bf(v.x) | ((unsigned)f2bf(v.y) << 16);
    w.y = (unsigned)f2bf(v.z) | ((unsigned)f2bf(v.w) << 16);
    *(uint2*)(&sT[s][dc]) = w;
  }
  __syncthreads();
  ushort_t* VtB = Vt + ((size_t)b * Dz + d0) * Sz + s0;
  {
    int d = t >> 2, c = t & 3;      // 64 d-rows x 4 chunks of 8 s
    uint4 u;
    ushort_t* tp = (ushort_t*)&u;
#pragma unroll
    for (int j = 0; j < 8; ++j) tp[j] = sT[c * 8 + j][d];
    *(uint4*)(VtB + (size_t)d * Sz + c * 8) = u;
  }
}

// ---------------- attention ----------------
__global__ __launch_bounds__(512, 2)
void attn_flash(const float* __restrict__ Q, const int* __restrict__ Msk,
                const ushort_t* __restrict__ Khi, const ushort_t* __restrict__ Klo,
                const ushort_t* __restrict__ Vt,
                float* __restrict__ Opart, float* __restrict__ Mpart,
                float* __restrict__ Lpart) {
  __shared__ ushort_t sKh[TS][KP];
  __shared__ ushort_t sKl[TS][KP];
  __shared__ ushort_t sVt[Dz][VP];
  __shared__ ushort_t sP[QT][PP];
  __shared__ float sTMax[2][QT];
  __shared__ float sTSum[2][QT];
  __shared__ float sM[QT];
  __shared__ float sL[QT];

  const int tid  = threadIdx.x;
  const int wave = tid >> 6;
  const int lane = tid & 63;
  const int l16  = lane & 15;
  const int quad = lane >> 4;
  const int rw   = wave >> 1;  // 0..3 : q row-tile of 16
  const int cw   = wave & 1;   // 0..1 : s col-tile (QK) / d half (PV)
  const int bx   = blockIdx.x;
  const int b    = bx >> 5;
  const int r5   = bx & 31;
  const int qt   = r5 >> 1;    // 0..15
  const int sh   = r5 & 1;     // S half
  const int q0   = qt * QT;
  const int sbeg = sh * (Sz / 2);
  const int send = sbeg + (Sz / 2);

  const float*    Qb  = Q   + ((size_t)b * NQz + q0) * Dz;
  const ushort_t* KhB = Khi + (size_t)b * Sz * Dz;
  const ushort_t* KlB = Klo + (size_t)b * Sz * Dz;
  const ushort_t* VtB = Vt  + (size_t)b * Dz * Sz;
  const int*      Mb  = Msk + ((size_t)b * NQz + q0) * (size_t)Sz;

  // ---- Q A-frags (rows rw*16+l16), hi/lo bf16 split ----
  bf16x8 qhi[16], qlo[16];
  {
    const float* qrow = Qb + (size_t)(rw * 16 + l16) * Dz;
#pragma unroll
    for (int kk = 0; kk < 16; ++kk) {
      const float4 a = *(const float4*)(qrow + kk * 32 + quad * 8);
      const float4 c = *(const float4*)(qrow + kk * 32 + quad * 8 + 4);
      float v[8] = {a.x, a.y, a.z, a.w, c.x, c.y, c.z, c.w};
      bf16x8 h, l;
#pragma unroll
      for (int j = 0; j < 8; ++j) {
        unsigned short hb = f2bf(v[j]);
        h[j] = (short)hb;
        l[j] = (short)f2bf(v[j] - bf2f(hb));
      }
      qhi[kk] = h;
      qlo[kk] = l;
    }
  }

  if (tid < QT) { sM[tid] = -1e30f; sL[tid] = 0.0f; }

  f32x4 oacc[16];
#pragma unroll
  for (int t = 0; t < 16; ++t) oacc[t] = (f32x4){0.f, 0.f, 0.f, 0.f};

  for (int s0 = sbeg; s0 < send; s0 += TS) {
    __syncthreads();  // prev-tile LDS reads done; sM/sL updates visible

    // ---- stage Khi, Klo (32 rows x 1024B), Vt (512 rows x 64B): uint4 copies ----
#pragma unroll
    for (int i = 0; i < 4; ++i) {
      int idx = tid + 512 * i;        // 0..2047
      int row = idx >> 6;             // 0..31
      int c16 = (idx & 63) * 8;       // ushort offset, 16B chunks
      *(uint4*)(&sKh[row][c16]) = *(const uint4*)(KhB + (size_t)(s0 + row) * Dz + c16);
    }
#pragma unroll
    for (int i = 0; i < 4; ++i) {
      int idx = tid + 512 * i;
      int row = idx >> 6;
      int c16 = (idx & 63) * 8;
      *(uint4*)(&sKl[row][c16]) = *(const uint4*)(KlB + (size_t)(s0 + row) * Dz + c16);
    }
#pragma unroll
    for (int i = 0; i < 4; ++i) {
      int idx = tid + 512 * i;        // 0..2047
      int d   = idx >> 2;             // 0..511
      int c   = idx & 3;              // chunk of 8 s
      *(uint4*)(&sVt[d][c * 8]) = *(const uint4*)(VtB + (size_t)d * Sz + s0 + c * 8);
    }
    __syncthreads();

    // ---- QK^T tile (rw, cw): 3-MFMA split over 16 k-steps ----
    f32x4 sc = (f32x4){0.f, 0.f, 0.f, 0.f};
    {
      const ushort_t* kh = &sKh[cw * 16 + l16][quad * 8];
      const ushort_t* kl = &sKl[cw * 16 + l16][quad * 8];
#pragma unroll
      for (int kk = 0; kk < 16; ++kk) {
        bf16x8 bh = *(const bf16x8*)(kh + kk * 32);
        bf16x8 bl = *(const bf16x8*)(kl + kk * 32);
        sc = __builtin_amdgcn_mfma_f32_16x16x32_bf16(qhi[kk], bh, sc, 0, 0, 0);
        sc = __builtin_amdgcn_mfma_f32_16x16x32_bf16(qlo[kk], bh, sc, 0, 0, 0);
        sc = __builtin_amdgcn_mfma_f32_16x16x32_bf16(qhi[kk], bl, sc, 0, 0, 0);
      }
    }

    // ---- mask + per-row tile max ----
    int   msk[4];
    float se[4];
#pragma unroll
    for (int r = 0; r < 4; ++r) {
      int qrow = rw * 16 + quad * 4 + r;
      msk[r] = Mb[(size_t)qrow * Sz + s0 + cw * 16 + l16];
      se[r]  = msk[r] ? sc[r] : -1e30f;
    }
    float rmax[4] = {se[0], se[1], se[2], se[3]};
#pragma unroll
    for (int d = 1; d < 16; d <<= 1) {
#pragma unroll
      for (int r = 0; r < 4; ++r) rmax[r] = fmaxf(rmax[r], __shfl_xor(rmax[r], d));
    }
    if (l16 == 0) {
#pragma unroll
      for (int r = 0; r < 4; ++r) sTMax[cw][rw * 16 + quad * 4 + r] = rmax[r];
    }
    __syncthreads();

    // ---- m_new, alpha, P, partial sums ----
    float mnew[4], alpha[4], rsum[4];
#pragma unroll
    for (int r = 0; r < 4; ++r) {
      int row = rw * 16 + quad * 4 + r;
      float mo = sM[row];
      float mn = fmaxf(mo, fmaxf(sTMax[0][row], sTMax[1][row]));
      mnew[r]  = mn;
      alpha[r] = __expf(mo - mn);
      float pv = msk[r] ? __expf(sc[r] - mn) : 0.0f;
      unsigned short pb = f2bf(pv);
      sP[row][cw * 16 + l16] = pb;
      rsum[r] = bf2f(pb);
    }
#pragma unroll
    for (int d = 1; d < 16; d <<= 1) {
#pragma unroll
      for (int r = 0; r < 4; ++r) rsum[r] += __shfl_xor(rsum[r], d);
    }
    if (l16 == 0) {
#pragma unroll
      for (int r = 0; r < 4; ++r) sTSum[cw][rw * 16 + quad * 4 + r] = rsum[r];
    }
    __syncthreads();

    if (cw == 0 && l16 == 0) {
#pragma unroll
      for (int r = 0; r < 4; ++r) {
        int row = rw * 16 + quad * 4 + r;
        sL[row] = alpha[r] * sL[row] + sTSum[0][row] + sTSum[1][row];
        sM[row] = mnew[r];
      }
    }

    // ---- O *= alpha; O += P·V (wave covers d-half cw) ----
#pragma unroll
    for (int t = 0; t < 16; ++t) {
#pragma unroll
      for (int r = 0; r < 4; ++r) oacc[t][r] *= alpha[r];
    }
    bf16x8 pa = *(const bf16x8*)(&sP[rw * 16 + l16][quad * 8]);
#pragma unroll
    for (int t = 0; t < 16; ++t) {
      bf16x8 vb = *(const bf16x8*)(&sVt[cw * 256 + t * 16 + l16][quad * 8]);
      oacc[t] = __builtin_amdgcn_mfma_f32_16x16x32_bf16(pa, vb, oacc[t], 0, 0, 0);
    }
  }

  __syncthreads();  // final sL/sM visible
  // unnormalized partials out
  const size_t rbase = (size_t)(b * 2 + sh) * NQz + q0;
#pragma unroll
  for (int t = 0; t < 16; ++t) {
#pragma unroll
    for (int r = 0; r < 4; ++r) {
      int rowq = rw * 16 + quad * 4 + r;
      Opart[(rbase + rowq) * Dz + cw * 256 + t * 16 + l16] = oacc[t][r];
    }
  }
  if (tid < QT) {
    Mpart[rbase + tid] = sM[tid];
    Lpart[rbase + tid] = sL[tid];
  }
}

// ---------------- combine the two S-halves ----------------
__global__ __launch_bounds__(256)
void combine(const float* __restrict__ Opart, const float* __restrict__ Mpart,
             const float* __restrict__ Lpart, float* __restrict__ Out) {
  int gid = blockIdx.x * 256 + threadIdx.x;   // 1,048,576 total
  int row = gid >> 7;                          // 0..8191 (b*1024+q)
  int b   = row >> 10;
  int q   = row & 1023;
  int c   = (gid & 127) * 4;
  size_t i0 = (size_t)(b * 2 + 0) * NQz + q;
  size_t i1 = (size_t)(b * 2 + 1) * NQz + q;
  float m0 = Mpart[i0], m1 = Mpart[i1];
  float l0 = Lpart[i0], l1 = Lpart[i1];
  float m  = fmaxf(m0, m1);
  float w0 = __expf(m0 - m), w1 = __expf(m1 - m);
  float inv = 1.0f / (w0 * l0 + w1 * l1);
  float4 a = *(const float4*)(Opart + i0 * Dz + c);
  float4 bv = *(const float4*)(Opart + i1 * Dz + c);
  float4 o;
  o.x = (w0 * a.x + w1 * bv.x) * inv;
  o.y = (w0 * a.y + w1 * bv.y) * inv;
  o.z = (w0 * a.z + w1 * bv.z) * inv;
  o.w = (w0 * a.w + w1 * bv.w) * inv;
  *(float4*)(Out + ((size_t)b * NQz + q) * Dz + c) = o;
}

extern "C" void kernel_launch(void* const* d_in, const int* in_sizes, int n_in,
                              void* d_out, int out_size, void* d_ws, size_t ws_size,
                              hipStream_t stream) {
  const float* Q = (const float*)d_in[0];
  const float* K = (const float*)d_in[1];
  const float* V = (const float*)d_in[2];
  const int*   M = (const int*)d_in[3];
  float* O = (float*)d_out;

  const size_t NKV = (size_t)Bz * Sz * Dz;  // 8.39M elements
  ushort_t* Khi = (ushort_t*)d_ws;
  ushort_t* Klo = Khi + NKV;
  ushort_t* Vt  = Klo + NKV;
  float* Opart  = (float*)(Vt + NKV);
  float* Mpart  = Opart + (size_t)Bz * 2 * NQz * Dz;
  float* Lpart  = Mpart + (size_t)Bz * 2 * NQz;

  prep_k<<<dim3((unsigned)(NKV / 1024)), dim3(256), 0, stream>>>(K, Khi, Klo);
  prep_v<<<dim3(Bz * 64 * 8), dim3(256), 0, stream>>>(V, Vt);
  attn_flash<<<dim3(256), dim3(512), 0, stream>>>(Q, M, Khi, Klo, Vt, Opart, Mpart, Lpart);
  combine<<<dim3(4096), dim3(256), 0, stream>>>(Opart, Mpart, Lpart, O);
}

// Round 3
// 346.107 us; speedup vs baseline: 3.6987x; 1.2341x over previous
//
#include <hip/hip_runtime.h>

// Masked attention B=8, NQ=1024, S=2048, D=512, fp32 in/out.
// prep_k: K -> Khi/Klo bf16 split. prep_v: V -> Vt bf16 [b][d][s].
// attn_flash: flash online masked softmax; QK = 3-MFMA split-bf16; PV bf16.
//   Async global_load_lds staging (K single-buf issued post-B3, V parity
//   double-buf issued post-B1), 2 barriers/tile, per-wave softmax stats with
//   deferred cross-half rescale at PV read. combine: merge 2 S-halves.

#define Bz 8
#define NQz 1024
#define Sz 2048
#define Dz 512
#define QT 64
#define TS 32
#define NT 32          // s-tiles per WG: (Sz/2)/TS
#define KP 520         // sK row pitch (ushort); 1040B rows
#define PP 40

typedef short bf16x8 __attribute__((ext_vector_type(8)));
typedef float f32x4 __attribute__((ext_vector_type(4)));
typedef unsigned short ushort_t;

#define AS1(p) ((const __attribute__((address_space(1))) unsigned int*)(p))
#define AS3(p) ((__attribute__((address_space(3))) unsigned int*)(p))

__device__ __forceinline__ unsigned short f2bf(float x) {
  unsigned u = __builtin_bit_cast(unsigned, x);
  unsigned r = (u + 0x7FFFu + ((u >> 16) & 1u)) >> 16;  // RNE
  return (unsigned short)r;
}
__device__ __forceinline__ float bf2f(unsigned short h) {
  unsigned u = ((unsigned)h) << 16;
  return __builtin_bit_cast(float, u);
}

// ---------------- prep 1: K fp32 -> Khi, Klo bf16 ----------------
__global__ __launch_bounds__(256)
void prep_k(const float* __restrict__ K, ushort_t* __restrict__ Khi,
            ushort_t* __restrict__ Klo) {
  size_t e = ((size_t)blockIdx.x * 256 + threadIdx.x) * 4;
  float4 v = *(const float4*)(K + e);
  float vv[4] = {v.x, v.y, v.z, v.w};
  unsigned short h[4], l[4];
#pragma unroll
  for (int j = 0; j < 4; ++j) {
    h[j] = f2bf(vv[j]);
    l[j] = f2bf(vv[j] - bf2f(h[j]));
  }
  uint2 hw, lw;
  hw.x = (unsigned)h[0] | ((unsigned)h[1] << 16);
  hw.y = (unsigned)h[2] | ((unsigned)h[3] << 16);
  lw.x = (unsigned)l[0] | ((unsigned)l[1] << 16);
  lw.y = (unsigned)l[2] | ((unsigned)l[3] << 16);
  *(uint2*)(Khi + e) = hw;
  *(uint2*)(Klo + e) = lw;
}

// ---------------- prep 2: V fp32 [b][s][d] -> Vt bf16 [b][d][s] ----------------
__global__ __launch_bounds__(256)
void prep_v(const float* __restrict__ V, ushort_t* __restrict__ Vt) {
  __shared__ ushort_t sT[32][72];
  const int t = threadIdx.x;
  const int bx = blockIdx.x;
  const int b = bx >> 9;
  const int rest = bx & 511;
  const int st = rest >> 3;
  const int dt = rest & 7;
  const int s0 = st * 32, d0 = dt * 64;
  const float* Vb = V + ((size_t)b * Sz + s0) * Dz + d0;
#pragma unroll
  for (int i = 0; i < 2; ++i) {
    int idx = t + 256 * i;
    int s = idx >> 4;
    int dc = (idx & 15) * 4;
    float4 v = *(const float4*)(Vb + (size_t)s * Dz + dc);
    uint2 w;
    w.x = (unsigned)f2bf(v.x) | ((unsigned)f2bf(v.y) << 16);
    w.y = (unsigned)f2bf(v.z) | ((unsigned)f2bf(v.w) << 16);
    *(uint2*)(&sT[s][dc]) = w;
  }
  __syncthreads();
  ushort_t* VtB = Vt + ((size_t)b * Dz + d0) * Sz + s0;
  {
    int d = t >> 2, c = t & 3;
    uint4 u;
    ushort_t* tp = (ushort_t*)&u;
#pragma unroll
    for (int j = 0; j < 8; ++j) tp[j] = sT[c * 8 + j][d];
    *(uint4*)(VtB + (size_t)d * Sz + c * 8) = u;
  }
}

// ---------------- attention ----------------
__global__ __launch_bounds__(512, 2)
void attn_flash(const float* __restrict__ Q, const int* __restrict__ Msk,
                const ushort_t* __restrict__ Khi, const ushort_t* __restrict__ Klo,
                const ushort_t* __restrict__ Vt,
                float* __restrict__ Opart, float* __restrict__ Mpart,
                float* __restrict__ Lpart) {
  __shared__ ushort_t sKh[TS][KP];
  __shared__ ushort_t sKl[TS][KP];
  __shared__ ushort_t sVt[2][Dz][TS];   // parity double-buffer, pitch 64B (DMA-contiguous)
  __shared__ ushort_t sP[QT][PP];
  __shared__ float sTMax[2][QT];        // per-col-half tile max
  __shared__ float sTSum[2][QT];        // per-col-half tile expsum (own-max referenced)
  __shared__ float sM[2][QT];           // running max, parity buffered
  __shared__ float sL[2][QT];           // running denom, parity buffered

  const int tid  = threadIdx.x;
  const int wave = tid >> 6;
  const int lane = tid & 63;
  const int l16  = lane & 15;
  const int quad = lane >> 4;
  const int rw   = wave >> 1;  // q row-tile of 16
  const int cw   = wave & 1;   // s col-half (QK) / d half (PV)
  const int bx   = blockIdx.x;
  const int b    = bx >> 5;
  const int r5   = bx & 31;
  const int qt   = r5 >> 1;
  const int sh   = r5 & 1;
  const int q0   = qt * QT;
  const int sbeg = sh * (Sz / 2);

  const float*    Qb  = Q   + ((size_t)b * NQz + q0) * Dz;
  const ushort_t* KhB = Khi + (size_t)b * Sz * Dz;
  const ushort_t* KlB = Klo + (size_t)b * Sz * Dz;
  const ushort_t* VtB = Vt  + (size_t)b * Dz * Sz;
  const int*      Mb  = Msk + ((size_t)b * NQz + q0) * (size_t)Sz;

  int msk_r[4];

  // async stagers: LDS dest is wave-uniform base + lane*16 (HW rule)
  auto issue_k = [&](int s0n) {
#pragma unroll
    for (int j = 0; j < 4; ++j) {
      int row = wave * 4 + j;
      const ushort_t* gph = KhB + (size_t)(s0n + row) * Dz + lane * 8;
      const ushort_t* gpl = KlB + (size_t)(s0n + row) * Dz + lane * 8;
      __builtin_amdgcn_global_load_lds(AS1(gph), AS3(&sKh[row][0]), 16, 0, 0);
      __builtin_amdgcn_global_load_lds(AS1(gpl), AS3(&sKl[row][0]), 16, 0, 0);
    }
  };
  auto issue_vt = [&](int s0n, int buf) {
#pragma unroll
    for (int j = 0; j < 4; ++j) {
      int dbase = wave * 64 + j * 16;
      const ushort_t* gp =
          VtB + (size_t)(dbase + (lane >> 2)) * Sz + s0n + (lane & 3) * 8;
      __builtin_amdgcn_global_load_lds(AS1(gp), AS3(&sVt[buf][dbase][0]), 16, 0, 0);
    }
  };
  auto load_mask = [&](int s0n) {
#pragma unroll
    for (int r = 0; r < 4; ++r) {
      int qrow = rw * 16 + quad * 4 + r;
      msk_r[r] = Mb[(size_t)qrow * Sz + s0n + cw * 16 + l16];
    }
  };

  // prologue: get tile-0 staging in flight before the heavy Q load
  issue_vt(sbeg, 0);
  issue_k(sbeg);
  load_mask(sbeg);

  // Q A-frags (rows rw*16+l16), hi/lo bf16 split — in registers for all of K=512
  bf16x8 qhi[16], qlo[16];
  {
    const float* qrow = Qb + (size_t)(rw * 16 + l16) * Dz;
#pragma unroll
    for (int kk = 0; kk < 16; ++kk) {
      const float4 a = *(const float4*)(qrow + kk * 32 + quad * 8);
      const float4 c = *(const float4*)(qrow + kk * 32 + quad * 8 + 4);
      float v[8] = {a.x, a.y, a.z, a.w, c.x, c.y, c.z, c.w};
      bf16x8 h, l;
#pragma unroll
      for (int j = 0; j < 8; ++j) {
        unsigned short hb = f2bf(v[j]);
        h[j] = (short)hb;
        l[j] = (short)f2bf(v[j] - bf2f(hb));
      }
      qhi[kk] = h;
      qlo[kk] = l;
    }
  }

  if (tid < QT) { sM[0][tid] = -1e30f; sL[0][tid] = 0.0f; }

  f32x4 oacc[16];
#pragma unroll
  for (int t = 0; t < 16; ++t) oacc[t] = (f32x4){0.f, 0.f, 0.f, 0.f};

  int p = 0;
  for (int i = 0; i < NT; ++i) {
    const int s0 = sbeg + i * TS;
    const int sNext = (i + 1 < NT) ? s0 + TS : sbeg;  // clamped; junk unread

    __syncthreads();  // B1: drains DMA (K, Vt, mask ready); prev-tile LDS reads done

    issue_vt(sNext, (i + 1) & 1);  // overlaps QK+phaseA; lands by B3 drain

    // ---- QK^T tile (rw, cw): 3-MFMA split over 16 k-steps ----
    f32x4 sc = (f32x4){0.f, 0.f, 0.f, 0.f};
    {
      const ushort_t* kh = &sKh[cw * 16 + l16][quad * 8];
      const ushort_t* kl = &sKl[cw * 16 + l16][quad * 8];
#pragma unroll
      for (int kk = 0; kk < 16; ++kk) {
        bf16x8 bh = *(const bf16x8*)(kh + kk * 32);
        bf16x8 bl = *(const bf16x8*)(kl + kk * 32);
        sc = __builtin_amdgcn_mfma_f32_16x16x32_bf16(qhi[kk], bh, sc, 0, 0, 0);
        sc = __builtin_amdgcn_mfma_f32_16x16x32_bf16(qlo[kk], bh, sc, 0, 0, 0);
        sc = __builtin_amdgcn_mfma_f32_16x16x32_bf16(qhi[kk], bl, sc, 0, 0, 0);
      }
    }

    // ---- phase A: mask, per-wave (16-col) max + expsum, write P' ----
    float se[4];
#pragma unroll
    for (int r = 0; r < 4; ++r) se[r] = msk_r[r] ? sc[r] : -1e30f;
    float rmax[4] = {se[0], se[1], se[2], se[3]};
#pragma unroll
    for (int d = 1; d < 16; d <<= 1) {
#pragma unroll
      for (int r = 0; r < 4; ++r) rmax[r] = fmaxf(rmax[r], __shfl_xor(rmax[r], d));
    }
    float rsum[4];
#pragma unroll
    for (int r = 0; r < 4; ++r) {
      int row = rw * 16 + quad * 4 + r;
      float pv = msk_r[r] ? __expf(sc[r] - rmax[r]) : 0.0f;
      unsigned short pb = f2bf(pv);
      sP[row][cw * 16 + l16] = pb;
      rsum[r] = bf2f(pb);
    }
#pragma unroll
    for (int d = 1; d < 16; d <<= 1) {
#pragma unroll
      for (int r = 0; r < 4; ++r) rsum[r] += __shfl_xor(rsum[r], d);
    }
    if (l16 == 0) {
#pragma unroll
      for (int r = 0; r < 4; ++r) {
        int row = rw * 16 + quad * 4 + r;
        sTMax[cw][row] = rmax[r];
        sTSum[cw][row] = rsum[r];
      }
    }

    __syncthreads();  // B3

    issue_k(sNext);    // sKh/sKl reads done at B3; lands by next B1 drain
    load_mask(sNext);  // msk_r consumed in phase A above

    // ---- phase B: merge stats, deferred-rescale P A-frag, PV ----
    const int pr = p;
    {
      const int row16 = rw * 16 + l16;
      float t0v = sTMax[0][row16], t1v = sTMax[1][row16];
      float mo16 = sM[pr][row16];
      float mn16 = fmaxf(mo16, fmaxf(t0v, t1v));
      float scl = __expf(((quad >> 1) ? t1v : t0v) - mn16);
      bf16x8 praw = *(const bf16x8*)(&sP[row16][quad * 8]);
      bf16x8 pa;
#pragma unroll
      for (int j = 0; j < 8; ++j) {
        float f = bf2f((ushort_t)praw[j]) * scl;
        pa[j] = (short)f2bf(f);
      }
      float alpha[4];
#pragma unroll
      for (int r = 0; r < 4; ++r) {
        int rc = rw * 16 + quad * 4 + r;
        float a0 = sTMax[0][rc], a1 = sTMax[1][rc];
        float mo = sM[pr][rc];
        float mn = fmaxf(mo, fmaxf(a0, a1));
        float al = __expf(mo - mn);
        alpha[r] = al;
        if (cw == 0 && l16 == 0) {
          sM[pr ^ 1][rc] = mn;
          sL[pr ^ 1][rc] = al * sL[pr][rc] + __expf(a0 - mn) * sTSum[0][rc]
                                           + __expf(a1 - mn) * sTSum[1][rc];
        }
      }
#pragma unroll
      for (int t = 0; t < 16; ++t) {
#pragma unroll
        for (int r = 0; r < 4; ++r) oacc[t][r] *= alpha[r];
      }
      const ushort_t(*vbuf)[TS] = sVt[i & 1];
#pragma unroll
      for (int t = 0; t < 16; ++t) {
        bf16x8 vb = *(const bf16x8*)(&vbuf[cw * 256 + t * 16 + l16][quad * 8]);
        oacc[t] = __builtin_amdgcn_mfma_f32_16x16x32_bf16(pa, vb, oacc[t], 0, 0, 0);
      }
    }
    p ^= 1;
  }

  __syncthreads();  // final sM/sL (in buffer p) visible
  const size_t rbase = (size_t)(b * 2 + sh) * NQz + q0;
#pragma unroll
  for (int t = 0; t < 16; ++t) {
#pragma unroll
    for (int r = 0; r < 4; ++r) {
      int rowq = rw * 16 + quad * 4 + r;
      Opart[(rbase + rowq) * Dz + cw * 256 + t * 16 + l16] = oacc[t][r];
    }
  }
  if (tid < QT) {
    Mpart[rbase + tid] = sM[p][tid];
    Lpart[rbase + tid] = sL[p][tid];
  }
}

// ---------------- combine the two S-halves ----------------
__global__ __launch_bounds__(256)
void combine(const float* __restrict__ Opart, const float* __restrict__ Mpart,
             const float* __restrict__ Lpart, float* __restrict__ Out) {
  int gid = blockIdx.x * 256 + threadIdx.x;
  int row = gid >> 7;
  int b   = row >> 10;
  int q   = row & 1023;
  int c   = (gid & 127) * 4;
  size_t i0 = (size_t)(b * 2 + 0) * NQz + q;
  size_t i1 = (size_t)(b * 2 + 1) * NQz + q;
  float m0 = Mpart[i0], m1 = Mpart[i1];
  float l0 = Lpart[i0], l1 = Lpart[i1];
  float m  = fmaxf(m0, m1);
  float w0 = __expf(m0 - m), w1 = __expf(m1 - m);
  float inv = 1.0f / (w0 * l0 + w1 * l1);
  float4 a = *(const float4*)(Opart + i0 * Dz + c);
  float4 bv = *(const float4*)(Opart + i1 * Dz + c);
  float4 o;
  o.x = (w0 * a.x + w1 * bv.x) * inv;
  o.y = (w0 * a.y + w1 * bv.y) * inv;
  o.z = (w0 * a.z + w1 * bv.z) * inv;
  o.w = (w0 * a.w + w1 * bv.w) * inv;
  *(float4*)(Out + ((size_t)b * NQz + q) * Dz + c) = o;
}

extern "C" void kernel_launch(void* const* d_in, const int* in_sizes, int n_in,
                              void* d_out, int out_size, void* d_ws, size_t ws_size,
                              hipStream_t stream) {
  const float* Q = (const float*)d_in[0];
  const float* K = (const float*)d_in[1];
  const float* V = (const float*)d_in[2];
  const int*   M = (const int*)d_in[3];
  float* O = (float*)d_out;

  const size_t NKV = (size_t)Bz * Sz * Dz;
  ushort_t* Khi = (ushort_t*)d_ws;
  ushort_t* Klo = Khi + NKV;
  ushort_t* Vt  = Klo + NKV;
  float* Opart  = (float*)(Vt + NKV);
  float* Mpart  = Opart + (size_t)Bz * 2 * NQz * Dz;
  float* Lpart  = Mpart + (size_t)Bz * 2 * NQz;

  prep_k<<<dim3((unsigned)(NKV / 1024)), dim3(256), 0, stream>>>(K, Khi, Klo);
  prep_v<<<dim3(Bz * 64 * 8), dim3(256), 0, stream>>>(V, Vt);
  attn_flash<<<dim3(256), dim3(512), 0, stream>>>(Q, M, Khi, Klo, Vt, Opart, Mpart, Lpart);
  combine<<<dim3(4096), dim3(256), 0, stream>>>(Opart, Mpart, Lpart, O);
}